// Round 9
// baseline (34.449 us; speedup 1.0000x reference)
//
#include <hip/hip_runtime.h>

#define IMG_H 1024
#define IMG_W 1024

// Streaming column-walk GradientVarianceLoss, fused single-kernel edition.
// 2048 waves = 16 images x 4 col-strips (256 cols) x 32 row-bands (32 rows).
// Each lane owns 4 columns; walks 34 input rows (band + 2 halo rows) for BOTH
// images; rolling separable Sobel (hA = [-1,0,1], hB = [1,2,1] horizontal;
// vertical combine at emit). One 4x4 block variance finalized every 4 rows.
// Loss reduced wave->block (LDS) -> one atomicAdd per block into d_out
// (zeroed via hipMemsetAsync each call). Evidence through R8 says this op is
// L3/fabric-BW-bound (~6 TB/s effective): dur tracks logical bytes, and
// TLP/ILP/instr-count changes are all null -> minimize bytes (+6.25% halo
// only) and launches (1 kernel).

struct RowRegs { float4 ma, mb; float la, ra_, lb, rb_; };
struct HAB { float hA[4]; float hB[4]; };

__global__ __launch_bounds__(256) void gvl_main(const float* __restrict__ A,
                                                const float* __restrict__ B,
                                                float* __restrict__ out) {
    const int t    = threadIdx.x;
    const int wave = (blockIdx.x << 2) | (t >> 6);   // 0..2047
    const int lane = t & 63;
    const int img   = wave >> 7;
    const int rem   = wave & 127;
    const int band  = rem >> 2;                      // 0..31, 32 rows each
    const int strip = rem & 3;                       // 0..3, 256 cols each
    const int y0    = band << 5;
    const int col0  = (strip << 8) | (lane << 2);

    const float* __restrict__ Ab = A + (size_t)img * (IMG_H * IMG_W);
    const float* __restrict__ Bb = B + (size_t)img * (IMG_H * IMG_W);

    const float mlc = (col0 > 0) ? 1.f : 0.f;            // left-col validity
    const float mrc = (col0 + 4 < IMG_W) ? 1.f : 0.f;    // right-col validity
    const int xl = (col0 > 0) ? col0 - 1 : 0;
    const int xr = (col0 + 4 < IMG_W) ? col0 + 4 : IMG_W - 1;
    const float zlast = (band == 31) ? 0.f : 1.f;        // row-1024 mask

    auto load_row = [&](int y, RowRegs& R) {
        int yc = y < IMG_H ? y : IMG_H - 1;              // clamp row 1024
        const float* ra = Ab + (size_t)yc * IMG_W;
        const float* rb = Bb + (size_t)yc * IMG_W;
        R.ma  = *reinterpret_cast<const float4*>(ra + col0);
        R.la  = ra[xl];  R.ra_ = ra[xr];
        R.mb  = *reinterpret_cast<const float4*>(rb + col0);
        R.lb  = rb[xl];  R.rb_ = rb[xr];
    };
    auto load_group = [&](RowRegs (&S)[4], int ys) {
#pragma unroll
        for (int r = 0; r < 4; ++r) load_row(ys + r, S[r]);
    };

    auto mk = [&](const float4 m, float l, float r, HAB& o) {
        float w0 = l * mlc, w5 = r * mrc;
        o.hA[0] = m.y - w0;  o.hA[1] = m.z - m.x;
        o.hA[2] = m.w - m.y; o.hA[3] = w5 - m.z;
        o.hB[0] = w0 + 2.f * m.x + m.y;
        o.hB[1] = m.x + 2.f * m.y + m.z;
        o.hB[2] = m.y + 2.f * m.z + m.w;
        o.hB[3] = m.z + 2.f * m.w + w5;
    };

    HAB a2, a1, b2, b1;   // carry: hA/hB of prev-2 and prev-1 input rows
    float loss = 0.f;

    auto emit = [&](const HAB& p2, const HAB& p1, const HAB& p0,
                    float& sX, float& sX2, float& sY, float& sY2) {
#pragma unroll
        for (int c = 0; c < 4; ++c) {
            float gx = p2.hA[c] + 2.f * p1.hA[c] + p0.hA[c];
            float gy = p0.hB[c] - p2.hB[c];
            sX += gx; sX2 += gx * gx;
            sY += gy; sY2 += gy * gy;
        }
    };

    auto do_group = [&](const RowRegs (&S)[4], float rm3) {
        float sXa = 0.f, sX2a = 0.f, sYa = 0.f, sY2a = 0.f;
        float sXb = 0.f, sX2b = 0.f, sYb = 0.f, sY2b = 0.f;
#pragma unroll
        for (int r = 0; r < 4; ++r) {
            HAB a0, b0;
            mk(S[r].ma, S[r].la, S[r].ra_, a0);
            mk(S[r].mb, S[r].lb, S[r].rb_, b0);
            if (r == 3) {   // possible image-bottom row (rm3==1.f folds away)
#pragma unroll
                for (int c = 0; c < 4; ++c) {
                    a0.hA[c] *= rm3; a0.hB[c] *= rm3;
                    b0.hA[c] *= rm3; b0.hB[c] *= rm3;
                }
            }
            emit(a2, a1, a0, sXa, sX2a, sYa, sY2a);
            emit(b2, b1, b0, sXb, sX2b, sYb, sY2b);
            a2 = a1; a1 = a0; b2 = b1; b1 = b0;
        }
        float mXa = sXa * 0.0625f, mYa = sYa * 0.0625f;
        float vXa = sX2a * 0.0625f - mXa * mXa;
        float vYa = sY2a * 0.0625f - mYa * mYa;
        float mXb = sXb * 0.0625f, mYb = sYb * 0.0625f;
        float vXb = sX2b * 0.0625f - mXb * mXb;
        float vYb = sY2b * 0.0625f - mYb * mYb;
        float dX = vXa - vXb, dY = vYa - vYb;
        loss += dX * dX + dY * dY;
    };

    // ---- prologue: rows y0-1, y0 + prefetch group 0 ----
    RowRegs P0, P1, N[4], M[4];
    const bool hasPrev = (band > 0);
    if (hasPrev) load_row(y0 - 1, P0);
    load_row(y0, P1);
    load_group(N, y0 + 1);
    if (hasPrev) {
        mk(P0.ma, P0.la, P0.ra_, a2);
        mk(P0.mb, P0.lb, P0.rb_, b2);
    } else {
#pragma unroll
        for (int c = 0; c < 4; ++c) { a2.hA[c] = a2.hB[c] = 0.f; b2.hA[c] = b2.hB[c] = 0.f; }
    }
    mk(P1.ma, P1.la, P1.ra_, a1);
    mk(P1.mb, P1.lb, P1.rb_, b1);

    // ---- 8 groups, software-pipelined (loads one group ahead) ----
#pragma unroll
    for (int i = 0; i < 4; ++i) {
        load_group(M, y0 + 8 * i + 5);             // group 2i+1 rows
        do_group(N, 1.f);                          // group 2i
        if (i < 3) load_group(N, y0 + 8 * i + 9);  // group 2i+2 rows
        do_group(M, (i == 3) ? zlast : 1.f);       // group 2i+1 (g7 may touch row 1024)
    }

    // ---- wave -> block reduction, one atomicAdd per block ----
#pragma unroll
    for (int off = 32; off > 0; off >>= 1) loss += __shfl_down(loss, off);
    __shared__ float ws[4];
    if (lane == 0) ws[t >> 6] = loss;
    __syncthreads();
    if (t == 0) atomicAdd(out, ws[0] + ws[1] + ws[2] + ws[3]);
}

extern "C" void kernel_launch(void* const* d_in, const int* in_sizes, int n_in,
                              void* d_out, int out_size, void* d_ws, size_t ws_size,
                              hipStream_t stream) {
    const float* out_img = (const float*)d_in[0];
    const float* tgt_img = (const float*)d_in[1];
    float* out = (float*)d_out;
    hipMemsetAsync(out, 0, sizeof(float), stream);   // accumulator must start at 0 each call
    gvl_main<<<512, 256, 0, stream>>>(out_img, tgt_img, out);
}

// Round 10
// 30.353 us; speedup vs baseline: 1.1349x; 1.1349x over previous
//
#include <hip/hip_runtime.h>

#define IMG_H 1024
#define IMG_W 1024

// Streaming column-walk GradientVarianceLoss, 64-row-band edition.
// 1024 waves = 16 images x 4 col-strips (256 cols) x 16 row-bands (64 rows).
// Each lane owns 4 columns; walks 66 input rows for BOTH images; rolling
// separable Sobel (hA = [-1,0,1], hB = [1,2,1] horizontal; vertical combine
// at emit). One 4x4 block variance finalized every 4 rows.
// Block = 4 vertically-adjacent bands of one strip -> 3/4 of halo-row
// re-reads hit the same CU's L1/L2. Halo over-read: 2/64 = 3.1%
// (vs 6.25% at 32-row bands). Regime is fabric-BW-bound (R5-R9 evidence):
// minimize bytes, ignore TLP.

struct RowRegs { float4 ma, mb; float la, ra_, lb, rb_; };
struct HAB { float hA[4]; float hB[4]; };

__global__ __launch_bounds__(256) void gvl_main(const float* __restrict__ A,
                                                const float* __restrict__ B,
                                                float* __restrict__ partial) {
    const int b    = blockIdx.x;                 // 0..255
    const int t    = threadIdx.x;
    const int w    = t >> 6;                     // wave in block, 0..3
    const int lane = t & 63;
    const int img   = b >> 4;                    // 0..15
    const int strip = (b >> 2) & 3;              // 0..3, 256 cols each
    const int quad  = b & 3;                     // 0..3, 256-row quadrant
    const int band  = (quad << 2) | w;           // 0..15, 64 rows each
    const int y0    = band << 6;
    const int col0  = (strip << 8) | (lane << 2);

    const float* __restrict__ Ab = A + (size_t)img * (IMG_H * IMG_W);
    const float* __restrict__ Bb = B + (size_t)img * (IMG_H * IMG_W);

    const float mlc = (col0 > 0) ? 1.f : 0.f;            // left-col validity
    const float mrc = (col0 + 4 < IMG_W) ? 1.f : 0.f;    // right-col validity
    const int xl = (col0 > 0) ? col0 - 1 : 0;
    const int xr = (col0 + 4 < IMG_W) ? col0 + 4 : IMG_W - 1;
    const float zlast = (band == 15) ? 0.f : 1.f;        // row-1024 mask

    auto load_row = [&](int y, RowRegs& R) {
        int yc = y < IMG_H ? y : IMG_H - 1;              // clamp row 1024
        const float* ra = Ab + (size_t)yc * IMG_W;
        const float* rb = Bb + (size_t)yc * IMG_W;
        R.ma  = *reinterpret_cast<const float4*>(ra + col0);
        R.la  = ra[xl];  R.ra_ = ra[xr];
        R.mb  = *reinterpret_cast<const float4*>(rb + col0);
        R.lb  = rb[xl];  R.rb_ = rb[xr];
    };
    auto load_group = [&](RowRegs (&S)[4], int ys) {
#pragma unroll
        for (int r = 0; r < 4; ++r) load_row(ys + r, S[r]);
    };

    auto mk = [&](const float4 m, float l, float r, HAB& o) {
        float w0 = l * mlc, w5 = r * mrc;
        o.hA[0] = m.y - w0;  o.hA[1] = m.z - m.x;
        o.hA[2] = m.w - m.y; o.hA[3] = w5 - m.z;
        o.hB[0] = w0 + 2.f * m.x + m.y;
        o.hB[1] = m.x + 2.f * m.y + m.z;
        o.hB[2] = m.y + 2.f * m.z + m.w;
        o.hB[3] = m.z + 2.f * m.w + w5;
    };

    HAB a2, a1, b2, b1;   // carry: hA/hB of prev-2 and prev-1 input rows
    float loss = 0.f;

    auto emit = [&](const HAB& p2, const HAB& p1, const HAB& p0,
                    float& sX, float& sX2, float& sY, float& sY2) {
#pragma unroll
        for (int c = 0; c < 4; ++c) {
            float gx = p2.hA[c] + 2.f * p1.hA[c] + p0.hA[c];
            float gy = p0.hB[c] - p2.hB[c];
            sX += gx; sX2 += gx * gx;
            sY += gy; sY2 += gy * gy;
        }
    };

    auto do_group = [&](const RowRegs (&S)[4], float rm3) {
        float sXa = 0.f, sX2a = 0.f, sYa = 0.f, sY2a = 0.f;
        float sXb = 0.f, sX2b = 0.f, sYb = 0.f, sY2b = 0.f;
#pragma unroll
        for (int r = 0; r < 4; ++r) {
            HAB a0, b0;
            mk(S[r].ma, S[r].la, S[r].ra_, a0);
            mk(S[r].mb, S[r].lb, S[r].rb_, b0);
            if (r == 3) {   // possible image-bottom row (rm3==1.f folds away)
#pragma unroll
                for (int c = 0; c < 4; ++c) {
                    a0.hA[c] *= rm3; a0.hB[c] *= rm3;
                    b0.hA[c] *= rm3; b0.hB[c] *= rm3;
                }
            }
            emit(a2, a1, a0, sXa, sX2a, sYa, sY2a);
            emit(b2, b1, b0, sXb, sX2b, sYb, sY2b);
            a2 = a1; a1 = a0; b2 = b1; b1 = b0;
        }
        float mXa = sXa * 0.0625f, mYa = sYa * 0.0625f;
        float vXa = sX2a * 0.0625f - mXa * mXa;
        float vYa = sY2a * 0.0625f - mYa * mYa;
        float mXb = sXb * 0.0625f, mYb = sYb * 0.0625f;
        float vXb = sX2b * 0.0625f - mXb * mXb;
        float vYb = sY2b * 0.0625f - mYb * mYb;
        float dX = vXa - vXb, dY = vYa - vYb;
        loss += dX * dX + dY * dY;
    };

    // ---- prologue: rows y0-1, y0 + prefetch group 0 ----
    RowRegs P0, P1, N[4], M[4];
    const bool hasPrev = (band > 0);
    if (hasPrev) load_row(y0 - 1, P0);
    load_row(y0, P1);
    load_group(N, y0 + 1);
    if (hasPrev) {
        mk(P0.ma, P0.la, P0.ra_, a2);
        mk(P0.mb, P0.lb, P0.rb_, b2);
    } else {
#pragma unroll
        for (int c = 0; c < 4; ++c) { a2.hA[c] = a2.hB[c] = 0.f; b2.hA[c] = b2.hB[c] = 0.f; }
    }
    mk(P1.ma, P1.la, P1.ra_, a1);
    mk(P1.mb, P1.lb, P1.rb_, b1);

    // ---- 16 groups (64 rows), software-pipelined (loads one group ahead) ----
#pragma unroll
    for (int i = 0; i < 8; ++i) {
        load_group(M, y0 + 8 * i + 5);             // group 2i+1 rows
        do_group(N, 1.f);                          // group 2i
        if (i < 7) load_group(N, y0 + 8 * i + 9);  // group 2i+2 rows
        do_group(M, (i == 7) ? zlast : 1.f);       // group 2i+1 (g15 may touch row 1024)
    }

    // ---- wave reduction, one partial per wave ----
#pragma unroll
    for (int off = 32; off > 0; off >>= 1) loss += __shfl_down(loss, off);
    if (lane == 0) partial[(b << 2) | w] = loss;
}

__global__ __launch_bounds__(256) void gvl_final(const float* __restrict__ partial,
                                                 float* __restrict__ out) {
    int t = threadIdx.x;
    float s = 0.f;
#pragma unroll
    for (int i = 0; i < 4; ++i) s += partial[t + (i << 8)];
#pragma unroll
    for (int off = 32; off > 0; off >>= 1) s += __shfl_down(s, off);
    __shared__ float ws[4];
    if ((t & 63) == 0) ws[t >> 6] = s;
    __syncthreads();
    if (t == 0) out[0] = ws[0] + ws[1] + ws[2] + ws[3];
}

extern "C" void kernel_launch(void* const* d_in, const int* in_sizes, int n_in,
                              void* d_out, int out_size, void* d_ws, size_t ws_size,
                              hipStream_t stream) {
    const float* out_img = (const float*)d_in[0];
    const float* tgt_img = (const float*)d_in[1];
    float* partial = (float*)d_ws;   // 1024 floats = 4 KB
    gvl_main<<<256, 256, 0, stream>>>(out_img, tgt_img, partial);
    gvl_final<<<1, 256, 0, stream>>>(partial, (float*)d_out);
}

// Round 11
// 28.775 us; speedup vs baseline: 1.1972x; 1.0548x over previous
//
#include <hip/hip_runtime.h>

#define IMG_H 1024
#define IMG_W 1024

// FINAL: Streaming column-walk GradientVarianceLoss (best variant, R5).
// 2048 waves = 16 images x 4 col-strips (256 cols) x 32 row-bands (32 rows).
// Each lane owns 4 columns; walks 34 input rows (band + 2 halo rows) for BOTH
// images; rolling separable Sobel (hA = [-1,0,1], hB = [1,2,1] horizontal;
// vertical combine at emit). One 4x4 block variance finalized every 4 rows.
// No LDS, no barriers; one group of loads ahead, straight-line unrolled.
// Evidence R5-R10: op is memory-system-bound at ~5.5 TB/s effective logical
// BW (88% of copy ceiling); TLP/ILP/instr-count/fusion levers all null or
// negative; 32-row bands = sweet spot (halo +6.25%, max L3 sharing).

struct RowRegs { float4 ma, mb; float la, ra_, lb, rb_; };
struct HAB { float hA[4]; float hB[4]; };

__global__ __launch_bounds__(256) void gvl_main(const float* __restrict__ A,
                                                const float* __restrict__ B,
                                                float* __restrict__ partial) {
    const int t    = threadIdx.x;
    const int wave = (blockIdx.x << 2) | (t >> 6);   // 0..2047
    const int lane = t & 63;
    const int img   = wave >> 7;
    const int rem   = wave & 127;
    const int band  = rem >> 2;                      // 0..31, 32 rows each
    const int strip = rem & 3;                       // 0..3, 256 cols each
    const int y0    = band << 5;
    const int col0  = (strip << 8) | (lane << 2);

    const float* __restrict__ Ab = A + (size_t)img * (IMG_H * IMG_W);
    const float* __restrict__ Bb = B + (size_t)img * (IMG_H * IMG_W);

    const float mlc = (col0 > 0) ? 1.f : 0.f;            // left-col validity
    const float mrc = (col0 + 4 < IMG_W) ? 1.f : 0.f;    // right-col validity
    const int xl = (col0 > 0) ? col0 - 1 : 0;
    const int xr = (col0 + 4 < IMG_W) ? col0 + 4 : IMG_W - 1;
    const float zlast = (band == 31) ? 0.f : 1.f;        // row-1024 mask

    auto load_row = [&](int y, RowRegs& R) {
        int yc = y < IMG_H ? y : IMG_H - 1;              // clamp row 1024
        const float* ra = Ab + (size_t)yc * IMG_W;
        const float* rb = Bb + (size_t)yc * IMG_W;
        R.ma  = *reinterpret_cast<const float4*>(ra + col0);
        R.la  = ra[xl];  R.ra_ = ra[xr];
        R.mb  = *reinterpret_cast<const float4*>(rb + col0);
        R.lb  = rb[xl];  R.rb_ = rb[xr];
    };
    auto load_group = [&](RowRegs (&S)[4], int ys) {
#pragma unroll
        for (int r = 0; r < 4; ++r) load_row(ys + r, S[r]);
    };

    auto mk = [&](const float4 m, float l, float r, HAB& o) {
        float w0 = l * mlc, w5 = r * mrc;
        o.hA[0] = m.y - w0;  o.hA[1] = m.z - m.x;
        o.hA[2] = m.w - m.y; o.hA[3] = w5 - m.z;
        o.hB[0] = w0 + 2.f * m.x + m.y;
        o.hB[1] = m.x + 2.f * m.y + m.z;
        o.hB[2] = m.y + 2.f * m.z + m.w;
        o.hB[3] = m.z + 2.f * m.w + w5;
    };

    HAB a2, a1, b2, b1;   // carry: hA/hB of prev-2 and prev-1 input rows
    float loss = 0.f;

    auto emit = [&](const HAB& p2, const HAB& p1, const HAB& p0,
                    float& sX, float& sX2, float& sY, float& sY2) {
#pragma unroll
        for (int c = 0; c < 4; ++c) {
            float gx = p2.hA[c] + 2.f * p1.hA[c] + p0.hA[c];
            float gy = p0.hB[c] - p2.hB[c];
            sX += gx; sX2 += gx * gx;
            sY += gy; sY2 += gy * gy;
        }
    };

    auto do_group = [&](const RowRegs (&S)[4], float rm3) {
        float sXa = 0.f, sX2a = 0.f, sYa = 0.f, sY2a = 0.f;
        float sXb = 0.f, sX2b = 0.f, sYb = 0.f, sY2b = 0.f;
#pragma unroll
        for (int r = 0; r < 4; ++r) {
            HAB a0, b0;
            mk(S[r].ma, S[r].la, S[r].ra_, a0);
            mk(S[r].mb, S[r].lb, S[r].rb_, b0);
            if (r == 3) {   // possible image-bottom row (rm3==1.f folds away)
#pragma unroll
                for (int c = 0; c < 4; ++c) {
                    a0.hA[c] *= rm3; a0.hB[c] *= rm3;
                    b0.hA[c] *= rm3; b0.hB[c] *= rm3;
                }
            }
            emit(a2, a1, a0, sXa, sX2a, sYa, sY2a);
            emit(b2, b1, b0, sXb, sX2b, sYb, sY2b);
            a2 = a1; a1 = a0; b2 = b1; b1 = b0;
        }
        float mXa = sXa * 0.0625f, mYa = sYa * 0.0625f;
        float vXa = sX2a * 0.0625f - mXa * mXa;
        float vYa = sY2a * 0.0625f - mYa * mYa;
        float mXb = sXb * 0.0625f, mYb = sYb * 0.0625f;
        float vXb = sX2b * 0.0625f - mXb * mXb;
        float vYb = sY2b * 0.0625f - mYb * mYb;
        float dX = vXa - vXb, dY = vYa - vYb;
        loss += dX * dX + dY * dY;
    };

    // ---- prologue: rows y0-1, y0 + prefetch group 0 ----
    RowRegs P0, P1, N[4], M[4];
    const bool hasPrev = (band > 0);
    if (hasPrev) load_row(y0 - 1, P0);
    load_row(y0, P1);
    load_group(N, y0 + 1);
    if (hasPrev) {
        mk(P0.ma, P0.la, P0.ra_, a2);
        mk(P0.mb, P0.lb, P0.rb_, b2);
    } else {
#pragma unroll
        for (int c = 0; c < 4; ++c) { a2.hA[c] = a2.hB[c] = 0.f; b2.hA[c] = b2.hB[c] = 0.f; }
    }
    mk(P1.ma, P1.la, P1.ra_, a1);
    mk(P1.mb, P1.lb, P1.rb_, b1);

    // ---- 8 groups, software-pipelined (loads one group ahead) ----
#pragma unroll
    for (int i = 0; i < 4; ++i) {
        load_group(M, y0 + 8 * i + 5);             // group 2i+1 rows
        do_group(N, 1.f);                          // group 2i
        if (i < 3) load_group(N, y0 + 8 * i + 9);  // group 2i+2 rows
        do_group(M, (i == 3) ? zlast : 1.f);       // group 2i+1 (g7 may touch row 1024)
    }

    // ---- wave reduction, one partial per wave ----
#pragma unroll
    for (int off = 32; off > 0; off >>= 1) loss += __shfl_down(loss, off);
    if (lane == 0) partial[wave] = loss;
}

__global__ __launch_bounds__(256) void gvl_final(const float* __restrict__ partial,
                                                 float* __restrict__ out) {
    int t = threadIdx.x;
    float s = 0.f;
#pragma unroll
    for (int i = 0; i < 8; ++i) s += partial[t + (i << 8)];
#pragma unroll
    for (int off = 32; off > 0; off >>= 1) s += __shfl_down(s, off);
    __shared__ float ws[4];
    if ((t & 63) == 0) ws[t >> 6] = s;
    __syncthreads();
    if (t == 0) out[0] = ws[0] + ws[1] + ws[2] + ws[3];
}

extern "C" void kernel_launch(void* const* d_in, const int* in_sizes, int n_in,
                              void* d_out, int out_size, void* d_ws, size_t ws_size,
                              hipStream_t stream) {
    const float* out_img = (const float*)d_in[0];
    const float* tgt_img = (const float*)d_in[1];
    float* partial = (float*)d_ws;   // 2048 floats = 8 KB
    gvl_main<<<512, 256, 0, stream>>>(out_img, tgt_img, partial);
    gvl_final<<<1, 256, 0, stream>>>(partial, (float*)d_out);
}